// Round 13
// baseline (548.946 us; speedup 1.0000x reference)
//
#include <hip/hip_runtime.h>
#include <hip/hip_bf16.h>
#include <stdint.h>

#define N_NODES 50000
#define F_IN 256
#define HID 128
#define NH 8
#define DH 16
#define NE 800000
#define NM 3
#define NOUT 8
#define NEG 0.2f
#define NROWS (N_NODES * NM)   // 150000 semantic rows
#define LDH 136                // padded bf16 stride for k_fcproj h-tile
#define BSH 8                  // bucket shift: 256 dst per bucket
#define NBUCK 196              // ceil(50000/256)
#define EPB 8192               // edges per binning block
#define SCB_ROWS 192           // k_semcomb rows/block = 64 whole nodes

// pack sizes (u16 elements per plane)
#define WFCP_N 65536           // 8ct * 8ks * 64 * 8
#define WSP_N  98304           // 3m * 8ct * 4ks * 64 * 8
#define UTP_N  6144            // 3m * 4ks * 64 * 8
#define W1P_N  16384           // 8ct * 4ks * 64 * 8 (Wsem1)

typedef __attribute__((ext_vector_type(8))) short bfrag;
typedef __attribute__((ext_vector_type(4))) float f32x4;
union FU { uint4 u; bfrag b; };

#define MFMA(a, b, c) __builtin_amdgcn_mfma_f32_16x16x32_bf16(a, b, c, 0, 0, 0)

__device__ __forceinline__ float bf2f(unsigned short u) {
    union { unsigned int ui; float f; } cv;
    cv.ui = ((unsigned int)u) << 16;
    return cv.f;
}
__device__ __forceinline__ unsigned short f2bf(float x) {
    __hip_bfloat16 b = __float2bfloat16(x);
    return reinterpret_cast<const unsigned short&>(b);
}
__device__ __forceinline__ float bflo(unsigned int u) {
    union { unsigned int x; float f; } c; c.x = u << 16; return c.f;
}
__device__ __forceinline__ float bfhi(unsigned int u) {
    union { unsigned int x; float f; } c; c.x = u & 0xffff0000u; return c.f;
}

// ---------------- CSR build (bucket-local, no per-edge global atomics) ------
// k_bhist: per-bucket histogram. LDS counters; 196 global atomics per block.
__global__ __launch_bounds__(256) void k_bhist(const int* __restrict__ dst0,
                                               int* __restrict__ bcnt) {
    __shared__ int cnt[NBUCK];
    int m = blockIdx.y;
    const int* dst = dst0 + (size_t)m * NE;
    int t = threadIdx.x;
    int e0 = blockIdx.x * EPB;
    int e1 = e0 + EPB; if (e1 > NE) e1 = NE;
    for (int i = t; i < NBUCK; i += 256) cnt[i] = 0;
    __syncthreads();
    for (int i = e0 + t; i < e1; i += 256)
        atomicAdd(&cnt[dst[i] >> BSH], 1);
    __syncthreads();
    for (int i = t; i < NBUCK; i += 256)
        if (cnt[i]) atomicAdd(&bcnt[m * NBUCK + i], cnt[i]);
}

// k_binA2: bin edges into bucket-contiguous pairs regions. Pairs packed to
// 4 B: src (16 bits) | in-bucket dst (8 bits) << 16.
__global__ __launch_bounds__(256) void k_binA2(const int* __restrict__ src0,
                                               const int* __restrict__ dst0,
                                               int* __restrict__ binCur0,
                                               unsigned int* __restrict__ pairs0) {
    __shared__ int cnt[NBUCK];
    __shared__ int base[NBUCK];
    int m = blockIdx.y;
    const int* src = src0 + (size_t)m * NE;
    const int* dst = dst0 + (size_t)m * NE;
    int* binCur = binCur0 + (size_t)m * NBUCK;
    unsigned int* pairs = pairs0 + (size_t)m * NE;
    int t = threadIdx.x;
    int e0 = blockIdx.x * EPB;
    int e1 = e0 + EPB; if (e1 > NE) e1 = NE;
    for (int i = t; i < NBUCK; i += 256) cnt[i] = 0;
    __syncthreads();
    for (int i = e0 + t; i < e1; i += 256)
        atomicAdd(&cnt[dst[i] >> BSH], 1);
    __syncthreads();
    for (int i = t; i < NBUCK; i += 256) {
        int c = cnt[i];
        base[i] = c ? atomicAdd(&binCur[i], c) : 0;
        cnt[i] = 0;
    }
    __syncthreads();
    for (int i = e0 + t; i < e1; i += 256) {
        int d = dst[i], s = src[i];
        int b = d >> BSH;
        int off = atomicAdd(&cnt[b], 1);
        pairs[base[b] + off] = (unsigned int)s | ((unsigned int)(d & 255) << 16);
    }
}

// k_csr: one block per (bucket, m). Per-dst hist + scan + scatter all in LDS.
__global__ __launch_bounds__(256) void k_csr(const unsigned int* __restrict__ pairs0,
                                             const int* __restrict__ bcnt,
                                             const int* __restrict__ bbase,
                                             int* __restrict__ offs0,
                                             int* __restrict__ ssrc0) {
    __shared__ int cnt[256];
    __shared__ int cur[256];
    int b = blockIdx.x, m = blockIdx.y, t = threadIdx.x;
    const unsigned int* pairs = pairs0 + (size_t)m * NE;
    int* offs = offs0 + (size_t)m * (N_NODES + 1);
    int* ssrc = ssrc0 + (size_t)m * NE;
    int pbase = bbase[m * NBUCK + b];
    int pend  = pbase + bcnt[m * NBUCK + b];
    cnt[t] = 0;
    __syncthreads();
    for (int i = pbase + t; i < pend; i += 256)
        atomicAdd(&cnt[pairs[i] >> 16], 1);
    __syncthreads();
    int v = cnt[t];
    __syncthreads();
    // inclusive scan of cnt in place
    #pragma unroll
    for (int o = 1; o < 256; o <<= 1) {
        int add = (t >= o) ? cnt[t - o] : 0;
        __syncthreads();
        cnt[t] += add;
        __syncthreads();
    }
    int ex = cnt[t] - v;           // exclusive prefix within bucket
    int dst0 = b << BSH;
    int nd = N_NODES - dst0; if (nd > 256) nd = 256;
    if (t < nd) offs[dst0 + t] = pbase + ex;
    if (b == NBUCK - 1 && t == 0) offs[N_NODES] = NE;
    cur[t] = pbase + ex;
    __syncthreads();
    for (int i = pbase + t; i < pend; i += 256) {
        unsigned int p = pairs[i];
        int pos = atomicAdd(&cur[p >> 16], 1);
        ssrc[pos] = (int)(p & 0xFFFFu);
    }
}

// ---- K_pack: pre-pack B matrices into MFMA fragment order as bf16 hi/lo planes.
// Blocks 51..53 additionally run the bucket-count scan (k_bscan folded in).
__global__ __launch_bounds__(256) void k_pack(const float* __restrict__ Wfc,
                                              const float* __restrict__ Wsrc,
                                              const float* __restrict__ Wdst,
                                              const float* __restrict__ al,
                                              const float* __restrict__ ar,
                                              const float* __restrict__ Wsem1,
                                              const int* __restrict__ bcnt,
                                              int* __restrict__ bbase,
                                              int* __restrict__ binCur,
                                              unsigned short* __restrict__ wfcph,
                                              unsigned short* __restrict__ wfcpl,
                                              unsigned short* __restrict__ wsph,
                                              unsigned short* __restrict__ wspl,
                                              unsigned short* __restrict__ utph,
                                              unsigned short* __restrict__ utpl,
                                              unsigned short* __restrict__ w1ph,
                                              unsigned short* __restrict__ w1pl) {
    __shared__ int sc[256];
    int g = blockIdx.x * 256 + threadIdx.x;
    if (blockIdx.x < 16) {                   // Wfc: 4096 slots (CT=8, KS=8)
        int s = g;
        int lane = s & 63, t = s >> 6;
        int ks = t & 7, ct = t >> 3;
        int n = ct * 16 + (lane & 15);
        int kb = ks * 32 + ((lane >> 4) << 3);
        #pragma unroll
        for (int j = 0; j < 8; j++) {
            float v = Wfc[(size_t)(kb + j) * HID + n];
            unsigned short h = f2bf(v);
            wfcph[(size_t)s * 8 + j] = h;
            wfcpl[(size_t)s * 8 + j] = f2bf(v - bf2f(h));
        }
    } else if (blockIdx.x < 40) {            // Wsrc: 6144 slots (3m, CT=8, KS=4)
        int s = g - 16 * 256;
        int lane = s & 63, t = s >> 6;
        int ks = t & 3, ct = (t >> 2) & 7, m = t >> 5;
        int n = ct * 16 + (lane & 15);
        int kb = ks * 32 + ((lane >> 4) << 3);
        #pragma unroll
        for (int j = 0; j < 8; j++) {
            float v = Wsrc[((size_t)m * HID + kb + j) * HID + n];
            unsigned short h = f2bf(v);
            wsph[(size_t)s * 8 + j] = h;
            wspl[(size_t)s * 8 + j] = f2bf(v - bf2f(h));
        }
    } else if (blockIdx.x < 43) {            // util|wtil: 768 slots (3m, KS=4)
        int s = g - 40 * 256;
        if (s >= UTP_N / 8) return;
        int lane = s & 63, t = s >> 6;
        int ks = t & 3, m = t >> 2;
        int n = lane & 15;
        int kb = ks * 32 + ((lane >> 4) << 3);
        int hh = n & 7;
        const float* W = (n < 8) ? Wsrc : Wdst;
        const float* a = (n < 8) ? al : ar;
        #pragma unroll
        for (int j = 0; j < 8; j++) {
            int k = kb + j;
            const float* wr = W + ((size_t)m * HID + k) * HID + hh * DH;
            const float* av = a + m * HID + hh * DH;
            float v = 0.f;
            #pragma unroll
            for (int d = 0; d < DH; d++) v += wr[d] * av[d];
            unsigned short h = f2bf(v);
            utph[(size_t)s * 8 + j] = h;
            utpl[(size_t)s * 8 + j] = f2bf(v - bf2f(h));
        }
    } else if (blockIdx.x < 51) {            // Wsem1: 2048 slots (CT=8, KS=4)
        int s = g - 43 * 256;
        int lane = s & 63, t = s >> 6;
        int ks = t & 3, ct = t >> 2;
        int n = ct * 16 + (lane & 15);
        int kb = ks * 32 + ((lane >> 4) << 3);
        #pragma unroll
        for (int j = 0; j < 8; j++) {
            float v = Wsem1[(size_t)(kb + j) * HID + n];
            unsigned short h = f2bf(v);
            w1ph[(size_t)s * 8 + j] = h;
            w1pl[(size_t)s * 8 + j] = f2bf(v - bf2f(h));
        }
    } else {                                 // bucket scan (ex-k_bscan), m = bx-51
        int m = blockIdx.x - 51, t = threadIdx.x;
        int v = (t < NBUCK) ? bcnt[m * NBUCK + t] : 0;
        sc[t] = v;
        __syncthreads();
        #pragma unroll
        for (int o = 1; o < 256; o <<= 1) {
            int add = (t >= o) ? sc[t - o] : 0;
            __syncthreads();
            sc[t] += add;
            __syncthreads();
        }
        if (t < NBUCK) {
            int p = sc[t] - v;
            bbase[m * NBUCK + t] = p;
            binCur[m * NBUCK + t] = p;
        }
    }
}

// ---- K1+K2 fused, MFMA. 64 rows/block, 4 waves = {row-half rw (32 rows)} x
// {col-half ch (4 col-tiles)}; each wave owns TWO 16-row A-tiles (rt=0,1).
// Layouts per m89/m91 (HW-verified round 7): A lane&15=row, k=(lane>>4)*8+j;
// C col=lane&15, row=(lane>>4)*4+reg.
__global__ __launch_bounds__(256) void k_fcproj(const float* __restrict__ A,
                                                const float* __restrict__ bias,
                                                const unsigned short* __restrict__ wfcph,
                                                const unsigned short* __restrict__ wfcpl,
                                                const unsigned short* __restrict__ wsph,
                                                const unsigned short* __restrict__ wspl,
                                                const unsigned short* __restrict__ utph,
                                                const unsigned short* __restrict__ utpl,
                                                unsigned short* __restrict__ fs0,
                                                float* __restrict__ el0,
                                                float* __restrict__ er0) {
    __shared__ unsigned short hb[64 * LDH];   // 17.4 KB bf16 h-tile
    int tid = threadIdx.x;
    int w = tid >> 6, l = tid & 63;
    int rw = w & 1;        // row half (32 rows)
    int ch = w >> 1;       // col half (ct base = ch*4)
    int lr = l & 15;       // A-row / C-col lane index
    int lq = l >> 4;       // k-block / C-row-quad index
    int r0 = blockIdx.x * 64;
    int gr[2];
    #pragma unroll
    for (int rt = 0; rt < 2; rt++) {
        int rowA = r0 + rw * 32 + rt * 16 + lr;
        gr[rt] = (rowA < N_NODES) ? rowA : (N_NODES - 1);
    }

    // ---- phase 1: h-tile = feat @ Wfc (split-precision MFMA) ----
    f32x4 acc[2][4];
    #pragma unroll
    for (int rt = 0; rt < 2; rt++)
        #pragma unroll
        for (int c = 0; c < 4; c++) acc[rt][c] = (f32x4){0.f, 0.f, 0.f, 0.f};
    const uint4* bh4 = (const uint4*)wfcph;
    const uint4* bl4 = (const uint4*)wfcpl;
    for (int ks = 0; ks < 8; ks++) {
        bfrag ah[2], al_[2];
        #pragma unroll
        for (int rt = 0; rt < 2; rt++) {
            const float* ap = A + (size_t)gr[rt] * F_IN + ks * 32 + lq * 8;
            float4 v0 = ((const float4*)ap)[0];
            float4 v1 = ((const float4*)ap)[1];
            float av[8] = {v0.x, v0.y, v0.z, v0.w, v1.x, v1.y, v1.z, v1.w};
            #pragma unroll
            for (int j = 0; j < 8; j++) {
                unsigned short h = f2bf(av[j]);
                ah[rt][j] = (short)h;
                al_[rt][j] = (short)f2bf(av[j] - bf2f(h));
            }
        }
        #pragma unroll
        for (int c = 0; c < 4; c++) {
            int ct = ch * 4 + c;
            FU bh, bl;
            bh.u = bh4[(ct * 8 + ks) * 64 + l];
            bl.u = bl4[(ct * 8 + ks) * 64 + l];
            #pragma unroll
            for (int rt = 0; rt < 2; rt++) {
                acc[rt][c] = MFMA(ah[rt], bh.b, acc[rt][c]);
                acc[rt][c] = MFMA(ah[rt], bl.b, acc[rt][c]);
                acc[rt][c] = MFMA(al_[rt], bh.b, acc[rt][c]);
            }
        }
    }
    // ---- phase 2: bf16(h + bias) -> LDS ----
    #pragma unroll
    for (int c = 0; c < 4; c++) {
        int col = (ch * 4 + c) * 16 + lr;
        float bb = bias[col];
        #pragma unroll
        for (int rt = 0; rt < 2; rt++)
            #pragma unroll
            for (int rg = 0; rg < 4; rg++) {
                int rloc = rw * 32 + rt * 16 + lq * 4 + rg;
                hb[rloc * LDH + col] = f2bf(acc[rt][c][rg] + bb);
            }
    }
    __syncthreads();
    // ---- phase 3: per-metapath fs16 / el / er ----
    const uint4* sh4 = (const uint4*)wsph;
    const uint4* sl4 = (const uint4*)wspl;
    const uint4* uh4 = (const uint4*)utph;
    const uint4* ul4 = (const uint4*)utpl;
    for (int m = 0; m < NM; m++) {
        f32x4 acc2[2][4];
        f32x4 eacc[2];
        #pragma unroll
        for (int rt = 0; rt < 2; rt++) {
            eacc[rt] = (f32x4){0.f, 0.f, 0.f, 0.f};
            #pragma unroll
            for (int c = 0; c < 4; c++) acc2[rt][c] = (f32x4){0.f, 0.f, 0.f, 0.f};
        }
        #pragma unroll
        for (int ks = 0; ks < 4; ks++) {
            FU a[2];
            #pragma unroll
            for (int rt = 0; rt < 2; rt++)
                a[rt].u = *(const uint4*)&hb[(rw * 32 + rt * 16 + lr) * LDH + ks * 32 + lq * 8];
            #pragma unroll
            for (int c = 0; c < 4; c++) {
                int ct = ch * 4 + c;
                FU bh, bl;
                bh.u = sh4[(m * 32 + ct * 4 + ks) * 64 + l];
                bl.u = sl4[(m * 32 + ct * 4 + ks) * 64 + l];
                #pragma unroll
                for (int rt = 0; rt < 2; rt++) {
                    acc2[rt][c] = MFMA(a[rt].b, bh.b, acc2[rt][c]);
                    acc2[rt][c] = MFMA(a[rt].b, bl.b, acc2[rt][c]);
                }
            }
            if (ch == 0) {
                FU uh, ul;
                uh.u = uh4[(m * 4 + ks) * 64 + l];
                ul.u = ul4[(m * 4 + ks) * 64 + l];
                #pragma unroll
                for (int rt = 0; rt < 2; rt++) {
                    eacc[rt] = MFMA(a[rt].b, uh.b, eacc[rt]);
                    eacc[rt] = MFMA(a[rt].b, ul.b, eacc[rt]);
                }
            }
        }
        unsigned short* fsm = fs0 + (size_t)m * N_NODES * HID;
        #pragma unroll
        for (int rt = 0; rt < 2; rt++)
            #pragma unroll
            for (int c = 0; c < 4; c++) {
                #pragma unroll
                for (int rg = 0; rg < 4; rg++) {
                    int row = r0 + rw * 32 + rt * 16 + lq * 4 + rg;
                    if (row < N_NODES)
                        fsm[(size_t)row * HID + (ch * 4 + c) * 16 + lr] = f2bf(acc2[rt][c][rg]);
                }
            }
        if (ch == 0) {
            float* elm = el0 + (size_t)m * N_NODES * NH;
            float* erm = er0 + (size_t)m * N_NODES * NH;
            #pragma unroll
            for (int rt = 0; rt < 2; rt++)
                #pragma unroll
                for (int rg = 0; rg < 4; rg++) {
                    int row = r0 + rw * 32 + rt * 16 + lq * 4 + rg;
                    if (row < N_NODES) {
                        if (lr < 8) elm[(size_t)row * NH + lr] = eacc[rt][rg];
                        else        erm[(size_t)row * NH + (lr - 8)] = eacc[rt][rg];
                    }
                }
        }
    }
}

// ---- K3: per-dst GAT aggregation. One WAVE per dst (2 dst per 128-thr block).
// At its random-gather regime ceiling (R10/R11 A-B: batching neutral) — frozen.
__global__ __launch_bounds__(128) void k_gat(const int* __restrict__ ssrc0,
                                             const int* __restrict__ offs0,
                                             const float* __restrict__ el0,
                                             const float* __restrict__ er0,
                                             const unsigned short* __restrict__ fs0,
                                             float* __restrict__ z) {
    int m = blockIdx.y;
    const int* ssrc = ssrc0 + (size_t)m * NE;
    const int* offs = offs0 + (size_t)m * (N_NODES + 1);
    const float* el = el0 + (size_t)m * N_NODES * NH;
    const float* er = er0 + (size_t)m * N_NODES * NH;
    const unsigned int* fsu = (const unsigned int*)(fs0 + (size_t)m * N_NODES * HID);
    int d = blockIdx.x * 2 + (threadIdx.x >> 6);
    int lane = threadIdx.x & 63;
    int hh = lane >> 3;          // head for features 2*lane, 2*lane+1
    int sub = lane & 7;          // edge slot within an 8-edge chunk
    int gbase = lane & 56;       // head-group base lane
    int s0 = offs[d], s1 = offs[d + 1];
    float erd = er[(unsigned)d * NH + hh];
    float num0 = 0.f, num1 = 0.f, denp = 0.f;
    int base = s0;
    for (; base + 8 <= s1; base += 8) {
        int s = ssrc[base + sub];
        float x = el[(unsigned)s * NH + hh] + erd;
        x = (x >= 0.f) ? x : NEG * x;
        float w = __expf(x);
        denp += w;
        int st[8]; float wt[8];
        #pragma unroll
        for (int t = 0; t < 8; t++) {
            st[t] = __shfl(s, gbase + t, 64);
            wt[t] = __shfl(w, gbase + t, 64);
        }
        unsigned int u[8];
        #pragma unroll
        for (int t = 0; t < 8; t++)
            u[t] = fsu[(unsigned)st[t] * (HID / 2) + lane];
        #pragma unroll
        for (int t = 0; t < 8; t++) {
            num0 += wt[t] * bflo(u[t]);
            num1 += wt[t] * bfhi(u[t]);
        }
    }
    int n = s1 - base;
    if (n > 0) {
        int s = ssrc[base + ((sub < n) ? sub : n - 1)];
        float x = el[(unsigned)s * NH + hh] + erd;
        x = (x >= 0.f) ? x : NEG * x;
        float w = (sub < n) ? __expf(x) : 0.f;
        denp += w;
        #pragma unroll 2
        for (int t = 0; t < n; t++) {
            int st = __shfl(s, gbase + t, 64);
            float wt = __shfl(w, gbase + t, 64);
            unsigned int u = fsu[(unsigned)st * (HID / 2) + lane];
            num0 += wt * bflo(u);
            num1 += wt * bfhi(u);
        }
    }
    denp += __shfl_xor(denp, 1, 64);
    denp += __shfl_xor(denp, 2, 64);
    denp += __shfl_xor(denp, 4, 64);
    float inv = 1.f / fmaxf(denp, 1e-9f);
    float v0 = num0 * inv, v1 = num1 * inv;
    v0 = (v0 > 0.f) ? v0 : (__expf(v0) - 1.f);
    v1 = (v1 > 0.f) ? v1 : (__expf(v1) - 1.f);
    *(float2*)&z[((size_t)d * NM + m) * HID + 2 * lane] = make_float2(v0, v1);
}

// ---- K4+K5 fused (k_semcomb v2): 384 thr = 6 waves x 32 rows (rt=2) =
// 192 rows = 64 whole nodes/block. W1 HI plane staged in LDS once per block
// (32 KB; all 6 waves reuse it); LO plane stays global and now fits L1
// exactly (32 KB working set). Round-12 counters showed each 16-row wave
// re-streamed 64 KB of B -> 600 MB L2 traffic, latency-bound (VALUBusy 11%).
// rt=2 additionally halves per-row B reads. Accumulation order per row
// unchanged (ks -> ct, hi then lo) -> bit-identical numerics.
__global__ __launch_bounds__(384) void k_semcomb(const float* __restrict__ A,
                                                 const unsigned short* __restrict__ w1ph,
                                                 const unsigned short* __restrict__ w1pl,
                                                 const float* __restrict__ b1,
                                                 const float* __restrict__ ws2,
                                                 const float* __restrict__ Wout,
                                                 const float* __restrict__ bout,
                                                 float* __restrict__ out) {
    __shared__ uint4 w1hL[W1P_N / 8];      // 2048 uint4 = 32 KB (hi plane)
    __shared__ float wsL[SCB_ROWS];
    __shared__ float fusedL[3][HID];
    int tid = threadIdx.x;
    // stage hi plane
    {
        const uint4* ph = (const uint4*)w1ph;
        for (int i = tid; i < W1P_N / 8; i += 384) w1hL[i] = ph[i];
    }
    int wv = tid >> 6, l = tid & 63;
    int lr = l & 15;
    int lq = l >> 4;
    int r0 = blockIdx.x * SCB_ROWS;
    int gr[2];
    #pragma unroll
    for (int rt = 0; rt < 2; rt++) {
        int rowA = r0 + wv * 32 + rt * 16 + lr;
        gr[rt] = (rowA < NROWS) ? rowA : (NROWS - 1);
    }
    const uint4* bl4 = (const uint4*)w1pl;
    f32x4 acc[2][8];
    #pragma unroll
    for (int rt = 0; rt < 2; rt++)
        #pragma unroll
        for (int ct = 0; ct < 8; ct++) acc[rt][ct] = (f32x4){0.f, 0.f, 0.f, 0.f};
    __syncthreads();   // staging visible
    #pragma unroll
    for (int ks = 0; ks < 4; ks++) {
        bfrag a[2];
        #pragma unroll
        for (int rt = 0; rt < 2; rt++) {
            const float* ap = A + (size_t)gr[rt] * HID + ks * 32 + lq * 8;
            float4 v0 = ((const float4*)ap)[0];
            float4 v1 = ((const float4*)ap)[1];
            float av[8] = {v0.x, v0.y, v0.z, v0.w, v1.x, v1.y, v1.z, v1.w};
            #pragma unroll
            for (int j = 0; j < 8; j++) a[rt][j] = (short)f2bf(av[j]);
        }
        #pragma unroll
        for (int ct = 0; ct < 8; ct++) {
            FU bh, bl;
            bh.u = w1hL[(ct * 4 + ks) * 64 + l];
            bl.u = bl4[(ct * 4 + ks) * 64 + l];
            #pragma unroll
            for (int rt = 0; rt < 2; rt++) {
                acc[rt][ct] = MFMA(a[rt], bh.b, acc[rt][ct]);
                acc[rt][ct] = MFMA(a[rt], bl.b, acc[rt][ct]);
            }
        }
    }
    float bb[8], s2[8];
    #pragma unroll
    for (int ct = 0; ct < 8; ct++) {
        bb[ct] = b1[ct * 16 + lr];
        s2[ct] = ws2[ct * 16 + lr];
    }
    #pragma unroll
    for (int rt = 0; rt < 2; rt++)
        #pragma unroll
        for (int rg = 0; rg < 4; rg++) {
            float v = 0.f;
            #pragma unroll
            for (int ct = 0; ct < 8; ct++)
                v += tanhf(acc[rt][ct][rg] + bb[ct]) * s2[ct];
            v += __shfl_xor(v, 1, 64);
            v += __shfl_xor(v, 2, 64);
            v += __shfl_xor(v, 4, 64);
            v += __shfl_xor(v, 8, 64);
            int row = r0 + wv * 32 + rt * 16 + lq * 4 + rg;
            if (lr == 0 && row < NROWS) wsL[row - r0] = v;
        }
    __syncthreads();
    // ---- phase B: beta softmax + fused + logits (3 nodes per pass, 64 total) ----
    int n0 = r0 / 3;               // 192 % 3 == 0 -> whole nodes per block
    int snb = tid >> 7;            // 0..2: node slot
    int j = tid & 127;
    #pragma unroll 1
    for (int p = 0; p < 22; p++) {
        int nn = p * 3 + snb;
        int n = n0 + nn;
        bool ok = (nn < 64) && (n < N_NODES);
        if (ok) {
            float w0 = wsL[nn * 3 + 0];
            float w1 = wsL[nn * 3 + 1];
            float w2 = wsL[nn * 3 + 2];
            float mx = fmaxf(w0, fmaxf(w1, w2));
            float e0 = __expf(w0 - mx);
            float e1 = __expf(w1 - mx);
            float e2 = __expf(w2 - mx);
            float inv = 1.f / (e0 + e1 + e2);
            size_t base = (size_t)n * NM * HID;
            float f = (e0 * A[base + j] + e1 * A[base + HID + j]
                       + e2 * A[base + 2 * HID + j]) * inv;
            fusedL[snb][j] = f;
        }
        __syncthreads();
        if (ok) {
            int c = j >> 4, t16 = j & 15;
            float pa = 0.f;
            #pragma unroll
            for (int i = 0; i < 8; i++) {
                int jj = t16 + i * 16;
                pa += fusedL[snb][jj] * Wout[jj * NOUT + c];
            }
            #pragma unroll
            for (int o = 8; o > 0; o >>= 1) pa += __shfl_down(pa, o, 16);
            if (t16 == 0) out[n * NOUT + c] = pa + bout[c];
        }
        __syncthreads();
    }
}

extern "C" void kernel_launch(void* const* d_in, const int* in_sizes, int n_in,
                              void* d_out, int out_size, void* d_ws, size_t ws_size,
                              hipStream_t stream) {
    (void)in_sizes; (void)n_in; (void)out_size; (void)ws_size;
    const float* feat  = (const float*)d_in[0];
    const float* Wfc   = (const float*)d_in[1];
    const float* bfc   = (const float*)d_in[2];
    const float* Wsrc  = (const float*)d_in[3];
    const float* Wdst  = (const float*)d_in[4];
    const float* al    = (const float*)d_in[5];
    const float* ar    = (const float*)d_in[6];
    const float* Wsem1 = (const float*)d_in[7];
    const float* bsem1 = (const float*)d_in[8];
    const float* wsem2 = (const float*)d_in[9];
    const float* Wout  = (const float*)d_in[10];
    const float* bout  = (const float*)d_in[11];
    const int* srcI    = (const int*)d_in[12];
    const int* dstI    = (const int*)d_in[13];
    float* out = (float*)d_out;

    // fp32 section.
    float* z    = (float*)d_ws;                       // NROWS*HID
    float* el   = z  + (size_t)NROWS * HID;           // NM*N_NODES*NH
    float* er   = el + (size_t)NM * N_NODES * NH;
    // packed bf16 hi/lo fragment planes
    unsigned short* wfcph = (unsigned short*)(er + (size_t)NM * N_NODES * NH);
    unsigned short* wfcpl = wfcph + WFCP_N;
    unsigned short* wsph  = wfcpl + WFCP_N;
    unsigned short* wspl  = wsph + WSP_N;
    unsigned short* utph  = wspl + WSP_N;
    unsigned short* utpl  = utph + UTP_N;
    unsigned short* w1ph  = utpl + UTP_N;
    unsigned short* w1pl  = w1ph + W1P_N;
    unsigned short* fs16  = w1pl + W1P_N;             // NM*N_NODES*HID
    // int section
    int* offs   = (int*)(fs16 + (size_t)NM * N_NODES * HID);
    int* ssrc   = offs   + (size_t)NM * (N_NODES + 1);
    int* bcnt   = ssrc   + (size_t)NM * NE;
    int* bbase  = bcnt   + (size_t)NM * NBUCK;
    int* binCur = bbase  + (size_t)NM * NBUCK;
    // pairs (NM*NE uint = 9.6 MB) aliases the fs16 region (38.4 MB): the CSR
    // build fully consumes pairs before k_fcproj writes fs16 (same stream).
    unsigned int* pairs = (unsigned int*)fs16;

    // ---- CSR build (bucket-local; zero per-edge global atomics) ----
    hipMemsetAsync(bcnt, 0, (size_t)NM * NBUCK * sizeof(int), stream);
    {
        dim3 gb((NE + EPB - 1) / EPB, NM);
        k_bhist<<<gb, 256, 0, stream>>>(dstI, bcnt);
        // k_pack blocks 51..53 also run the bucket scan (needs k_bhist done)
        k_pack<<<54, 256, 0, stream>>>(Wfc, Wsrc, Wdst, al, ar, Wsem1,
                                       bcnt, bbase, binCur,
                                       wfcph, wfcpl, wsph, wspl, utph, utpl,
                                       w1ph, w1pl);
        k_binA2<<<gb, 256, 0, stream>>>(srcI, dstI, binCur, pairs);
        dim3 gcs(NBUCK, NM);
        k_csr<<<gcs, 256, 0, stream>>>(pairs, bcnt, bbase, offs, ssrc);
    }

    k_fcproj<<<(N_NODES + 63) / 64, 256, 0, stream>>>(feat, bfc,
                                                      wfcph, wfcpl, wsph, wspl,
                                                      utph, utpl, fs16, el, er);
    {
        dim3 gg(N_NODES / 2, NM);
        k_gat<<<gg, 128, 0, stream>>>(ssrc, offs, el, er, fs16, z);
    }

    k_semcomb<<<(NROWS + SCB_ROWS - 1) / SCB_ROWS, 384, 0, stream>>>(
        z, w1ph, w1pl, bsem1, wsem2, Wout, bout, out);
}

// Round 14
// 423.389 us; speedup vs baseline: 1.2966x; 1.2966x over previous
//
#include <hip/hip_runtime.h>
#include <hip/hip_bf16.h>
#include <stdint.h>

#define N_NODES 50000
#define F_IN 256
#define HID 128
#define NH 8
#define DH 16
#define NE 800000
#define NM 3
#define NOUT 8
#define NEG 0.2f
#define NROWS (N_NODES * NM)   // 150000 semantic rows
#define LDH 136                // padded bf16 stride for k_fcproj h-tile
#define BSH 8                  // bucket shift: 256 dst per bucket
#define NBUCK 196              // ceil(50000/256)
#define EPB 8192               // edges per binning block
#define SCB_ROWS 96            // k_semcomb rows/block = 32 whole nodes

// pack sizes (u16 elements per plane)
#define WFCP_N 65536           // 8ct * 8ks * 64 * 8
#define WSP_N  98304           // 3m * 8ct * 4ks * 64 * 8
#define UTP_N  6144            // 3m * 4ks * 64 * 8
#define W1P_N  16384           // 8ct * 4ks * 64 * 8 (Wsem1)

typedef __attribute__((ext_vector_type(8))) short bfrag;
typedef __attribute__((ext_vector_type(4))) float f32x4;
union FU { uint4 u; bfrag b; };

#define MFMA(a, b, c) __builtin_amdgcn_mfma_f32_16x16x32_bf16(a, b, c, 0, 0, 0)

__device__ __forceinline__ float bf2f(unsigned short u) {
    union { unsigned int ui; float f; } cv;
    cv.ui = ((unsigned int)u) << 16;
    return cv.f;
}
__device__ __forceinline__ unsigned short f2bf(float x) {
    __hip_bfloat16 b = __float2bfloat16(x);
    return reinterpret_cast<const unsigned short&>(b);
}
__device__ __forceinline__ float bflo(unsigned int u) {
    union { unsigned int x; float f; } c; c.x = u << 16; return c.f;
}
__device__ __forceinline__ float bfhi(unsigned int u) {
    union { unsigned int x; float f; } c; c.x = u & 0xffff0000u; return c.f;
}

// ---------------- CSR build (bucket-local, no per-edge global atomics) ------
__global__ __launch_bounds__(256) void k_bhist(const int* __restrict__ dst0,
                                               int* __restrict__ bcnt) {
    __shared__ int cnt[NBUCK];
    int m = blockIdx.y;
    const int* dst = dst0 + (size_t)m * NE;
    int t = threadIdx.x;
    int e0 = blockIdx.x * EPB;
    int e1 = e0 + EPB; if (e1 > NE) e1 = NE;
    for (int i = t; i < NBUCK; i += 256) cnt[i] = 0;
    __syncthreads();
    for (int i = e0 + t; i < e1; i += 256)
        atomicAdd(&cnt[dst[i] >> BSH], 1);
    __syncthreads();
    for (int i = t; i < NBUCK; i += 256)
        if (cnt[i]) atomicAdd(&bcnt[m * NBUCK + i], cnt[i]);
}

// k_binA2: bin edges into bucket-contiguous pairs regions. Pairs packed to
// 4 B: src (16 bits) | in-bucket dst (8 bits) << 16.
__global__ __launch_bounds__(256) void k_binA2(const int* __restrict__ src0,
                                               const int* __restrict__ dst0,
                                               int* __restrict__ binCur0,
                                               unsigned int* __restrict__ pairs0) {
    __shared__ int cnt[NBUCK];
    __shared__ int base[NBUCK];
    int m = blockIdx.y;
    const int* src = src0 + (size_t)m * NE;
    const int* dst = dst0 + (size_t)m * NE;
    int* binCur = binCur0 + (size_t)m * NBUCK;
    unsigned int* pairs = pairs0 + (size_t)m * NE;
    int t = threadIdx.x;
    int e0 = blockIdx.x * EPB;
    int e1 = e0 + EPB; if (e1 > NE) e1 = NE;
    for (int i = t; i < NBUCK; i += 256) cnt[i] = 0;
    __syncthreads();
    for (int i = e0 + t; i < e1; i += 256)
        atomicAdd(&cnt[dst[i] >> BSH], 1);
    __syncthreads();
    for (int i = t; i < NBUCK; i += 256) {
        int c = cnt[i];
        base[i] = c ? atomicAdd(&binCur[i], c) : 0;
        cnt[i] = 0;
    }
    __syncthreads();
    for (int i = e0 + t; i < e1; i += 256) {
        int d = dst[i], s = src[i];
        int b = d >> BSH;
        int off = atomicAdd(&cnt[b], 1);
        pairs[base[b] + off] = (unsigned int)s | ((unsigned int)(d & 255) << 16);
    }
}

// k_csr: one block per (bucket, m). Per-dst hist + scan + scatter all in LDS.
__global__ __launch_bounds__(256) void k_csr(const unsigned int* __restrict__ pairs0,
                                             const int* __restrict__ bcnt,
                                             const int* __restrict__ bbase,
                                             int* __restrict__ offs0,
                                             int* __restrict__ ssrc0) {
    __shared__ int cnt[256];
    __shared__ int cur[256];
    int b = blockIdx.x, m = blockIdx.y, t = threadIdx.x;
    const unsigned int* pairs = pairs0 + (size_t)m * NE;
    int* offs = offs0 + (size_t)m * (N_NODES + 1);
    int* ssrc = ssrc0 + (size_t)m * NE;
    int pbase = bbase[m * NBUCK + b];
    int pend  = pbase + bcnt[m * NBUCK + b];
    cnt[t] = 0;
    __syncthreads();
    for (int i = pbase + t; i < pend; i += 256)
        atomicAdd(&cnt[pairs[i] >> 16], 1);
    __syncthreads();
    int v = cnt[t];
    __syncthreads();
    #pragma unroll
    for (int o = 1; o < 256; o <<= 1) {
        int add = (t >= o) ? cnt[t - o] : 0;
        __syncthreads();
        cnt[t] += add;
        __syncthreads();
    }
    int ex = cnt[t] - v;           // exclusive prefix within bucket
    int dst0 = b << BSH;
    int nd = N_NODES - dst0; if (nd > 256) nd = 256;
    if (t < nd) offs[dst0 + t] = pbase + ex;
    if (b == NBUCK - 1 && t == 0) offs[N_NODES] = NE;
    cur[t] = pbase + ex;
    __syncthreads();
    for (int i = pbase + t; i < pend; i += 256) {
        unsigned int p = pairs[i];
        int pos = atomicAdd(&cur[p >> 16], 1);
        ssrc[pos] = (int)(p & 0xFFFFu);
    }
}

// ---- K_pack: pre-pack B matrices into MFMA fragment order as bf16 hi/lo planes.
// Blocks 51..53 additionally run the bucket-count scan (k_bscan folded in).
__global__ __launch_bounds__(256) void k_pack(const float* __restrict__ Wfc,
                                              const float* __restrict__ Wsrc,
                                              const float* __restrict__ Wdst,
                                              const float* __restrict__ al,
                                              const float* __restrict__ ar,
                                              const float* __restrict__ Wsem1,
                                              const int* __restrict__ bcnt,
                                              int* __restrict__ bbase,
                                              int* __restrict__ binCur,
                                              unsigned short* __restrict__ wfcph,
                                              unsigned short* __restrict__ wfcpl,
                                              unsigned short* __restrict__ wsph,
                                              unsigned short* __restrict__ wspl,
                                              unsigned short* __restrict__ utph,
                                              unsigned short* __restrict__ utpl,
                                              unsigned short* __restrict__ w1ph,
                                              unsigned short* __restrict__ w1pl) {
    __shared__ int sc[256];
    int g = blockIdx.x * 256 + threadIdx.x;
    if (blockIdx.x < 16) {                   // Wfc: 4096 slots (CT=8, KS=8)
        int s = g;
        int lane = s & 63, t = s >> 6;
        int ks = t & 7, ct = t >> 3;
        int n = ct * 16 + (lane & 15);
        int kb = ks * 32 + ((lane >> 4) << 3);
        #pragma unroll
        for (int j = 0; j < 8; j++) {
            float v = Wfc[(size_t)(kb + j) * HID + n];
            unsigned short h = f2bf(v);
            wfcph[(size_t)s * 8 + j] = h;
            wfcpl[(size_t)s * 8 + j] = f2bf(v - bf2f(h));
        }
    } else if (blockIdx.x < 40) {            // Wsrc: 6144 slots (3m, CT=8, KS=4)
        int s = g - 16 * 256;
        int lane = s & 63, t = s >> 6;
        int ks = t & 3, ct = (t >> 2) & 7, m = t >> 5;
        int n = ct * 16 + (lane & 15);
        int kb = ks * 32 + ((lane >> 4) << 3);
        #pragma unroll
        for (int j = 0; j < 8; j++) {
            float v = Wsrc[((size_t)m * HID + kb + j) * HID + n];
            unsigned short h = f2bf(v);
            wsph[(size_t)s * 8 + j] = h;
            wspl[(size_t)s * 8 + j] = f2bf(v - bf2f(h));
        }
    } else if (blockIdx.x < 43) {            // util|wtil: 768 slots (3m, KS=4)
        int s = g - 40 * 256;
        if (s >= UTP_N / 8) return;
        int lane = s & 63, t = s >> 6;
        int ks = t & 3, m = t >> 2;
        int n = lane & 15;
        int kb = ks * 32 + ((lane >> 4) << 3);
        int hh = n & 7;
        const float* W = (n < 8) ? Wsrc : Wdst;
        const float* a = (n < 8) ? al : ar;
        #pragma unroll
        for (int j = 0; j < 8; j++) {
            int k = kb + j;
            const float* wr = W + ((size_t)m * HID + k) * HID + hh * DH;
            const float* av = a + m * HID + hh * DH;
            float v = 0.f;
            #pragma unroll
            for (int d = 0; d < DH; d++) v += wr[d] * av[d];
            unsigned short h = f2bf(v);
            utph[(size_t)s * 8 + j] = h;
            utpl[(size_t)s * 8 + j] = f2bf(v - bf2f(h));
        }
    } else if (blockIdx.x < 51) {            // Wsem1: 2048 slots (CT=8, KS=4)
        int s = g - 43 * 256;
        int lane = s & 63, t = s >> 6;
        int ks = t & 3, ct = t >> 2;
        int n = ct * 16 + (lane & 15);
        int kb = ks * 32 + ((lane >> 4) << 3);
        #pragma unroll
        for (int j = 0; j < 8; j++) {
            float v = Wsem1[(size_t)(kb + j) * HID + n];
            unsigned short h = f2bf(v);
            w1ph[(size_t)s * 8 + j] = h;
            w1pl[(size_t)s * 8 + j] = f2bf(v - bf2f(h));
        }
    } else {                                 // bucket scan (ex-k_bscan), m = bx-51
        int m = blockIdx.x - 51, t = threadIdx.x;
        int v = (t < NBUCK) ? bcnt[m * NBUCK + t] : 0;
        sc[t] = v;
        __syncthreads();
        #pragma unroll
        for (int o = 1; o < 256; o <<= 1) {
            int add = (t >= o) ? sc[t - o] : 0;
            __syncthreads();
            sc[t] += add;
            __syncthreads();
        }
        if (t < NBUCK) {
            int p = sc[t] - v;
            bbase[m * NBUCK + t] = p;
            binCur[m * NBUCK + t] = p;
        }
    }
}

// ---- K1+K2 fused, MFMA. 64 rows/block, 4 waves = {row-half rw (32 rows)} x
// {col-half ch (4 col-tiles)}; each wave owns TWO 16-row A-tiles (rt=0,1).
// Layouts per m89/m91 (HW-verified round 7): A lane&15=row, k=(lane>>4)*8+j;
// C col=lane&15, row=(lane>>4)*4+reg.
__global__ __launch_bounds__(256) void k_fcproj(const float* __restrict__ A,
                                                const float* __restrict__ bias,
                                                const unsigned short* __restrict__ wfcph,
                                                const unsigned short* __restrict__ wfcpl,
                                                const unsigned short* __restrict__ wsph,
                                                const unsigned short* __restrict__ wspl,
                                                const unsigned short* __restrict__ utph,
                                                const unsigned short* __restrict__ utpl,
                                                unsigned short* __restrict__ fs0,
                                                float* __restrict__ el0,
                                                float* __restrict__ er0) {
    __shared__ unsigned short hb[64 * LDH];   // 17.4 KB bf16 h-tile
    int tid = threadIdx.x;
    int w = tid >> 6, l = tid & 63;
    int rw = w & 1;        // row half (32 rows)
    int ch = w >> 1;       // col half (ct base = ch*4)
    int lr = l & 15;       // A-row / C-col lane index
    int lq = l >> 4;       // k-block / C-row-quad index
    int r0 = blockIdx.x * 64;
    int gr[2];
    #pragma unroll
    for (int rt = 0; rt < 2; rt++) {
        int rowA = r0 + rw * 32 + rt * 16 + lr;
        gr[rt] = (rowA < N_NODES) ? rowA : (N_NODES - 1);
    }

    // ---- phase 1: h-tile = feat @ Wfc (split-precision MFMA) ----
    f32x4 acc[2][4];
    #pragma unroll
    for (int rt = 0; rt < 2; rt++)
        #pragma unroll
        for (int c = 0; c < 4; c++) acc[rt][c] = (f32x4){0.f, 0.f, 0.f, 0.f};
    const uint4* bh4 = (const uint4*)wfcph;
    const uint4* bl4 = (const uint4*)wfcpl;
    for (int ks = 0; ks < 8; ks++) {
        bfrag ah[2], al_[2];
        #pragma unroll
        for (int rt = 0; rt < 2; rt++) {
            const float* ap = A + (size_t)gr[rt] * F_IN + ks * 32 + lq * 8;
            float4 v0 = ((const float4*)ap)[0];
            float4 v1 = ((const float4*)ap)[1];
            float av[8] = {v0.x, v0.y, v0.z, v0.w, v1.x, v1.y, v1.z, v1.w};
            #pragma unroll
            for (int j = 0; j < 8; j++) {
                unsigned short h = f2bf(av[j]);
                ah[rt][j] = (short)h;
                al_[rt][j] = (short)f2bf(av[j] - bf2f(h));
            }
        }
        #pragma unroll
        for (int c = 0; c < 4; c++) {
            int ct = ch * 4 + c;
            FU bh, bl;
            bh.u = bh4[(ct * 8 + ks) * 64 + l];
            bl.u = bl4[(ct * 8 + ks) * 64 + l];
            #pragma unroll
            for (int rt = 0; rt < 2; rt++) {
                acc[rt][c] = MFMA(ah[rt], bh.b, acc[rt][c]);
                acc[rt][c] = MFMA(ah[rt], bl.b, acc[rt][c]);
                acc[rt][c] = MFMA(al_[rt], bh.b, acc[rt][c]);
            }
        }
    }
    // ---- phase 2: bf16(h + bias) -> LDS ----
    #pragma unroll
    for (int c = 0; c < 4; c++) {
        int col = (ch * 4 + c) * 16 + lr;
        float bb = bias[col];
        #pragma unroll
        for (int rt = 0; rt < 2; rt++)
            #pragma unroll
            for (int rg = 0; rg < 4; rg++) {
                int rloc = rw * 32 + rt * 16 + lq * 4 + rg;
                hb[rloc * LDH + col] = f2bf(acc[rt][c][rg] + bb);
            }
    }
    __syncthreads();
    // ---- phase 3: per-metapath fs16 / el / er ----
    const uint4* sh4 = (const uint4*)wsph;
    const uint4* sl4 = (const uint4*)wspl;
    const uint4* uh4 = (const uint4*)utph;
    const uint4* ul4 = (const uint4*)utpl;
    for (int m = 0; m < NM; m++) {
        f32x4 acc2[2][4];
        f32x4 eacc[2];
        #pragma unroll
        for (int rt = 0; rt < 2; rt++) {
            eacc[rt] = (f32x4){0.f, 0.f, 0.f, 0.f};
            #pragma unroll
            for (int c = 0; c < 4; c++) acc2[rt][c] = (f32x4){0.f, 0.f, 0.f, 0.f};
        }
        #pragma unroll
        for (int ks = 0; ks < 4; ks++) {
            FU a[2];
            #pragma unroll
            for (int rt = 0; rt < 2; rt++)
                a[rt].u = *(const uint4*)&hb[(rw * 32 + rt * 16 + lr) * LDH + ks * 32 + lq * 8];
            #pragma unroll
            for (int c = 0; c < 4; c++) {
                int ct = ch * 4 + c;
                FU bh, bl;
                bh.u = sh4[(m * 32 + ct * 4 + ks) * 64 + l];
                bl.u = sl4[(m * 32 + ct * 4 + ks) * 64 + l];
                #pragma unroll
                for (int rt = 0; rt < 2; rt++) {
                    acc2[rt][c] = MFMA(a[rt].b, bh.b, acc2[rt][c]);
                    acc2[rt][c] = MFMA(a[rt].b, bl.b, acc2[rt][c]);
                }
            }
            if (ch == 0) {
                FU uh, ul;
                uh.u = uh4[(m * 4 + ks) * 64 + l];
                ul.u = ul4[(m * 4 + ks) * 64 + l];
                #pragma unroll
                for (int rt = 0; rt < 2; rt++) {
                    eacc[rt] = MFMA(a[rt].b, uh.b, eacc[rt]);
                    eacc[rt] = MFMA(a[rt].b, ul.b, eacc[rt]);
                }
            }
        }
        unsigned short* fsm = fs0 + (size_t)m * N_NODES * HID;
        #pragma unroll
        for (int rt = 0; rt < 2; rt++)
            #pragma unroll
            for (int c = 0; c < 4; c++) {
                #pragma unroll
                for (int rg = 0; rg < 4; rg++) {
                    int row = r0 + rw * 32 + rt * 16 + lq * 4 + rg;
                    if (row < N_NODES)
                        fsm[(size_t)row * HID + (ch * 4 + c) * 16 + lr] = f2bf(acc2[rt][c][rg]);
                }
            }
        if (ch == 0) {
            float* elm = el0 + (size_t)m * N_NODES * NH;
            float* erm = er0 + (size_t)m * N_NODES * NH;
            #pragma unroll
            for (int rt = 0; rt < 2; rt++)
                #pragma unroll
                for (int rg = 0; rg < 4; rg++) {
                    int row = r0 + rw * 32 + rt * 16 + lq * 4 + rg;
                    if (row < N_NODES) {
                        if (lr < 8) elm[(size_t)row * NH + lr] = eacc[rt][rg];
                        else        erm[(size_t)row * NH + (lr - 8)] = eacc[rt][rg];
                    }
                }
        }
    }
}

// ---- K3: per-dst GAT aggregation. One WAVE per dst (2 dst per 128-thr block).
// At its random-gather regime ceiling (R10/R11 A-B: batching neutral) — frozen.
__global__ __launch_bounds__(128) void k_gat(const int* __restrict__ ssrc0,
                                             const int* __restrict__ offs0,
                                             const float* __restrict__ el0,
                                             const float* __restrict__ er0,
                                             const unsigned short* __restrict__ fs0,
                                             float* __restrict__ z) {
    int m = blockIdx.y;
    const int* ssrc = ssrc0 + (size_t)m * NE;
    const int* offs = offs0 + (size_t)m * (N_NODES + 1);
    const float* el = el0 + (size_t)m * N_NODES * NH;
    const float* er = er0 + (size_t)m * N_NODES * NH;
    const unsigned int* fsu = (const unsigned int*)(fs0 + (size_t)m * N_NODES * HID);
    int d = blockIdx.x * 2 + (threadIdx.x >> 6);
    int lane = threadIdx.x & 63;
    int hh = lane >> 3;          // head for features 2*lane, 2*lane+1
    int sub = lane & 7;          // edge slot within an 8-edge chunk
    int gbase = lane & 56;       // head-group base lane
    int s0 = offs[d], s1 = offs[d + 1];
    float erd = er[(unsigned)d * NH + hh];
    float num0 = 0.f, num1 = 0.f, denp = 0.f;
    int base = s0;
    for (; base + 8 <= s1; base += 8) {
        int s = ssrc[base + sub];
        float x = el[(unsigned)s * NH + hh] + erd;
        x = (x >= 0.f) ? x : NEG * x;
        float w = __expf(x);
        denp += w;
        int st[8]; float wt[8];
        #pragma unroll
        for (int t = 0; t < 8; t++) {
            st[t] = __shfl(s, gbase + t, 64);
            wt[t] = __shfl(w, gbase + t, 64);
        }
        unsigned int u[8];
        #pragma unroll
        for (int t = 0; t < 8; t++)
            u[t] = fsu[(unsigned)st[t] * (HID / 2) + lane];
        #pragma unroll
        for (int t = 0; t < 8; t++) {
            num0 += wt[t] * bflo(u[t]);
            num1 += wt[t] * bfhi(u[t]);
        }
    }
    int n = s1 - base;
    if (n > 0) {
        int s = ssrc[base + ((sub < n) ? sub : n - 1)];
        float x = el[(unsigned)s * NH + hh] + erd;
        x = (x >= 0.f) ? x : NEG * x;
        float w = (sub < n) ? __expf(x) : 0.f;
        denp += w;
        #pragma unroll 2
        for (int t = 0; t < n; t++) {
            int st = __shfl(s, gbase + t, 64);
            float wt = __shfl(w, gbase + t, 64);
            unsigned int u = fsu[(unsigned)st * (HID / 2) + lane];
            num0 += wt * bflo(u);
            num1 += wt * bfhi(u);
        }
    }
    denp += __shfl_xor(denp, 1, 64);
    denp += __shfl_xor(denp, 2, 64);
    denp += __shfl_xor(denp, 4, 64);
    float inv = 1.f / fmaxf(denp, 1e-9f);
    float v0 = num0 * inv, v1 = num1 * inv;
    v0 = (v0 > 0.f) ? v0 : (__expf(v0) - 1.f);
    v1 = (v1 > 0.f) ? v1 : (__expf(v1) - 1.f);
    *(float2*)&z[((size_t)d * NM + m) * HID + 2 * lane] = make_float2(v0, v1);
}

// ---- K4+K5 fused (k_semcomb v3): 384 thr = 6 waves x 16 rows = 96 rows =
// 32 whole nodes/block (v1 shape; v2's LDS-staging bundle collapsed occupancy
// 52% -> 22% and regressed — reverted). Two latency fixes vs v1:
//  (a) phase A batches all 16 B-fragment loads (8 hi + 8 lo) of a k-step into
//      register arrays BEFORE the MFMAs — 16-deep MLP instead of the ~2 the
//      VGPR=32 allocation allowed (v1 counters: VALUBusy 10.8%, latency-bound).
//  (b) phase B is barrier-free: each wave owns ~5-6 whole nodes; fused goes to
//      a wave-private LDS row (intra-wave RAW, no __syncthreads); Wout dot via
//      8-lane shfl_xor reduce. Removes v1's 22 block-wide barriers.
// Phase A accumulation order unchanged -> w values bit-identical to v1.
__global__ __launch_bounds__(384) void k_semcomb(const float* __restrict__ A,
                                                 const unsigned short* __restrict__ w1ph,
                                                 const unsigned short* __restrict__ w1pl,
                                                 const float* __restrict__ b1,
                                                 const float* __restrict__ ws2,
                                                 const float* __restrict__ Wout,
                                                 const float* __restrict__ bout,
                                                 float* __restrict__ out) {
    __shared__ float wsL[SCB_ROWS];
    __shared__ float fwave[6][HID];
    int tid = threadIdx.x;
    int wv = tid >> 6, l = tid & 63;
    int lr = l & 15;
    int lq = l >> 4;
    int r0 = blockIdx.x * SCB_ROWS;
    int tbase = r0 + wv * 16;
    int rowA = tbase + lr;
    int gr = (rowA < NROWS) ? rowA : (NROWS - 1);
    const uint4* bh4 = (const uint4*)w1ph;
    const uint4* bl4 = (const uint4*)w1pl;
    f32x4 acc[8];
    #pragma unroll
    for (int ct = 0; ct < 8; ct++) acc[ct] = (f32x4){0.f, 0.f, 0.f, 0.f};
    #pragma unroll
    for (int ks = 0; ks < 4; ks++) {
        const float* ap = A + (size_t)gr * HID + ks * 32 + lq * 8;
        float4 v0 = ((const float4*)ap)[0];
        float4 v1 = ((const float4*)ap)[1];
        float av[8] = {v0.x, v0.y, v0.z, v0.w, v1.x, v1.y, v1.z, v1.w};
        bfrag a;
        #pragma unroll
        for (int j = 0; j < 8; j++) a[j] = (short)f2bf(av[j]);
        FU bh[8], bl[8];
        #pragma unroll
        for (int ct = 0; ct < 8; ct++) {
            bh[ct].u = bh4[(ct * 4 + ks) * 64 + l];
            bl[ct].u = bl4[(ct * 4 + ks) * 64 + l];
        }
        #pragma unroll
        for (int ct = 0; ct < 8; ct++) {
            acc[ct] = MFMA(a, bh[ct].b, acc[ct]);
            acc[ct] = MFMA(a, bl[ct].b, acc[ct]);
        }
    }
    float bb[8], s2[8];
    #pragma unroll
    for (int ct = 0; ct < 8; ct++) {
        bb[ct] = b1[ct * 16 + lr];
        s2[ct] = ws2[ct * 16 + lr];
    }
    #pragma unroll
    for (int rg = 0; rg < 4; rg++) {
        float v = 0.f;
        #pragma unroll
        for (int ct = 0; ct < 8; ct++)
            v += tanhf(acc[ct][rg] + bb[ct]) * s2[ct];
        v += __shfl_xor(v, 1, 64);
        v += __shfl_xor(v, 2, 64);
        v += __shfl_xor(v, 4, 64);
        v += __shfl_xor(v, 8, 64);
        int row = tbase + lq * 4 + rg;
        if (lr == 0 && row < NROWS) wsL[row - r0] = v;
    }
    __syncthreads();
    // ---- phase B: per-wave nodes, barrier-free ----
    int n0 = r0 / 3;               // 96 % 3 == 0 -> whole nodes per block
    float* fw = fwave[wv];
    for (int nn = wv; nn < 32; nn += 6) {
        int n = n0 + nn;
        if (n >= N_NODES) break;
        float w0 = wsL[nn * 3 + 0];
        float w1 = wsL[nn * 3 + 1];
        float w2 = wsL[nn * 3 + 2];
        float mx = fmaxf(w0, fmaxf(w1, w2));
        float e0 = __expf(w0 - mx);
        float e1 = __expf(w1 - mx);
        float e2 = __expf(w2 - mx);
        float inv = 1.f / (e0 + e1 + e2);
        size_t base = (size_t)n * NM * HID;
        float f0 = (e0 * A[base + l] + e1 * A[base + HID + l]
                    + e2 * A[base + 2 * HID + l]) * inv;
        int l2 = l + 64;
        float f1 = (e0 * A[base + l2] + e1 * A[base + HID + l2]
                    + e2 * A[base + 2 * HID + l2]) * inv;
        fw[l] = f0;
        fw[l2] = f1;
        // intra-wave LDS RAW: compiler inserts lgkmcnt wait; lockstep wave
        int c = l & 7, s = l >> 3;
        float pa = 0.f;
        #pragma unroll
        for (int i = 0; i < 16; i++) {
            int jj = s + 8 * i;
            pa += fw[jj] * Wout[jj * NOUT + c];
        }
        pa += __shfl_xor(pa, 8, 64);
        pa += __shfl_xor(pa, 16, 64);
        pa += __shfl_xor(pa, 32, 64);
        if (s == 0) out[n * NOUT + c] = pa + bout[c];
    }
}

extern "C" void kernel_launch(void* const* d_in, const int* in_sizes, int n_in,
                              void* d_out, int out_size, void* d_ws, size_t ws_size,
                              hipStream_t stream) {
    (void)in_sizes; (void)n_in; (void)out_size; (void)ws_size;
    const float* feat  = (const float*)d_in[0];
    const float* Wfc   = (const float*)d_in[1];
    const float* bfc   = (const float*)d_in[2];
    const float* Wsrc  = (const float*)d_in[3];
    const float* Wdst  = (const float*)d_in[4];
    const float* al    = (const float*)d_in[5];
    const float* ar    = (const float*)d_in[6];
    const float* Wsem1 = (const float*)d_in[7];
    const float* bsem1 = (const float*)d_in[8];
    const float* wsem2 = (const float*)d_in[9];
    const float* Wout  = (const float*)d_in[10];
    const float* bout  = (const float*)d_in[11];
    const int* srcI    = (const int*)d_in[12];
    const int* dstI    = (const int*)d_in[13];
    float* out = (float*)d_out;

    // fp32 section.
    float* z    = (float*)d_ws;                       // NROWS*HID
    float* el   = z  + (size_t)NROWS * HID;           // NM*N_NODES*NH
    float* er   = el + (size_t)NM * N_NODES * NH;
    // packed bf16 hi/lo fragment planes
    unsigned short* wfcph = (unsigned short*)(er + (size_t)NM * N_NODES * NH);
    unsigned short* wfcpl = wfcph + WFCP_N;
    unsigned short* wsph  = wfcpl + WFCP_N;
    unsigned short* wspl  = wsph + WSP_N;
    unsigned short* utph  = wspl + WSP_N;
    unsigned short* utpl  = utph + UTP_N;
    unsigned short* w1ph  = utpl + UTP_N;
    unsigned short* w1pl  = w1ph + W1P_N;
    unsigned short* fs16  = w1pl + W1P_N;             // NM*N_NODES*HID
    // int section
    int* offs   = (int*)(fs16 + (size_t)NM * N_NODES * HID);
    int* ssrc   = offs   + (size_t)NM * (N_NODES + 1);
    int* bcnt   = ssrc   + (size_t)NM * NE;
    int* bbase  = bcnt   + (size_t)NM * NBUCK;
    int* binCur = bbase  + (size_t)NM * NBUCK;
    // pairs (NM*NE uint = 9.6 MB) aliases the fs16 region (38.4 MB): the CSR
    // build fully consumes pairs before k_fcproj writes fs16 (same stream).
    unsigned int* pairs = (unsigned int*)fs16;

    // ---- CSR build (bucket-local; zero per-edge global atomics) ----
    hipMemsetAsync(bcnt, 0, (size_t)NM * NBUCK * sizeof(int), stream);
    {
        dim3 gb((NE + EPB - 1) / EPB, NM);
        k_bhist<<<gb, 256, 0, stream>>>(dstI, bcnt);
        // k_pack blocks 51..53 also run the bucket scan (needs k_bhist done)
        k_pack<<<54, 256, 0, stream>>>(Wfc, Wsrc, Wdst, al, ar, Wsem1,
                                       bcnt, bbase, binCur,
                                       wfcph, wfcpl, wsph, wspl, utph, utpl,
                                       w1ph, w1pl);
        k_binA2<<<gb, 256, 0, stream>>>(srcI, dstI, binCur, pairs);
        dim3 gcs(NBUCK, NM);
        k_csr<<<gcs, 256, 0, stream>>>(pairs, bcnt, bbase, offs, ssrc);
    }

    k_fcproj<<<(N_NODES + 63) / 64, 256, 0, stream>>>(feat, bfc,
                                                      wfcph, wfcpl, wsph, wspl,
                                                      utph, utpl, fs16, el, er);
    {
        dim3 gg(N_NODES / 2, NM);
        k_gat<<<gg, 128, 0, stream>>>(ssrc, offs, el, er, fs16, z);
    }

    k_semcomb<<<(NROWS + SCB_ROWS - 1) / SCB_ROWS, 384, 0, stream>>>(
        z, w1ph, w1pl, bsem1, wsem2, Wout, bout, out);
}